// Round 11
// baseline (462.828 us; speedup 1.0000x reference)
//
#include <hip/hip_runtime.h>
#include <hip/hip_fp16.h>

typedef unsigned short ushort_t;
typedef unsigned int uint_t;
typedef _Float16 f16_t;
typedef __attribute__((ext_vector_type(8))) _Float16 f16x8;
typedef __attribute__((ext_vector_type(4))) float f32x4;

__device__ __forceinline__ float2 h2f2(uint_t u) {
  __half2 h = *reinterpret_cast<__half2*>(&u);
  return __half22float2(h);
}
__device__ __forceinline__ uint_t f2h2(float a, float b) {
  __half2 h = __floats2half2_rn(a, b);
  return *reinterpret_cast<uint_t*>(&h);
}

// ---------- CSR construction (no global atomics: LDS-privatized counting sort) ----------
template <int RSIZE, int NR>
__global__ __launch_bounds__(256) void k_cnt(const int* __restrict__ key, int* __restrict__ cnt,
                                             int n, int slen) {
  __shared__ int h[RSIZE];
  const int s = blockIdx.x / NR, r = blockIdx.x % NR;
  const int base = r * RSIZE;
  for (int i = threadIdx.x; i < RSIZE; i += 256) h[i] = 0;
  __syncthreads();
  const int i0 = s * slen, i1 = min(n, i0 + slen);
  for (int i = i0 + threadIdx.x * 4; i < i1; i += 1024) {
    int4 k4;
    if (i + 3 < i1) {
      k4 = *reinterpret_cast<const int4*>(&key[i]);
    } else {
      k4.x = key[i];
      k4.y = (i + 1 < i1) ? key[i + 1] : -1;
      k4.z = (i + 2 < i1) ? key[i + 2] : -1;
      k4.w = (i + 3 < i1) ? key[i + 3] : -1;
    }
    int d;
    d = k4.x - base; if ((unsigned)d < (unsigned)RSIZE) atomicAdd(&h[d], 1);
    d = k4.y - base; if ((unsigned)d < (unsigned)RSIZE) atomicAdd(&h[d], 1);
    d = k4.z - base; if ((unsigned)d < (unsigned)RSIZE) atomicAdd(&h[d], 1);
    d = k4.w - base; if ((unsigned)d < (unsigned)RSIZE) atomicAdd(&h[d], 1);
  }
  __syncthreads();
  const int NB = RSIZE * NR;
  for (int i = threadIdx.x; i < RSIZE; i += 256) cnt[(size_t)s * NB + base + i] = h[i];
}

// per-bin exclusive scan over slices (edge CSR)
__global__ void k_combine(int* __restrict__ cnt, int* __restrict__ deg, int nb, int nslice) {
  int d = blockIdx.x * 256 + threadIdx.x;
  if (d >= nb) return;
  int acc = 0;
  for (int s = 0; s < nslice; s++) {
    int c = cnt[(size_t)s * nb + d];
    cnt[(size_t)s * nb + d] = acc;
    acc += c;
  }
  deg[d] = acc;
}

// hierarchical scan, pass 1
__global__ __launch_bounds__(1024) void k_scan1(const int* __restrict__ deg, int* __restrict__ rowptr,
                                                int* __restrict__ blksum, int n) {
  __shared__ int wtot[16];
  const int tid = threadIdx.x, lane = tid & 63, w = tid >> 6;
  const int i = blockIdx.x * 1024 + tid;
  int v = (i < n) ? deg[i] : 0;
  int incl = v;
#pragma unroll
  for (int off = 1; off < 64; off <<= 1) {
    int t = __shfl_up(incl, off, 64);
    if (lane >= off) incl += t;
  }
  if (lane == 63) wtot[w] = incl;
  __syncthreads();
  if (w == 0) {
    int tv = (lane < 16) ? wtot[lane] : 0;
#pragma unroll
    for (int off = 1; off < 16; off <<= 1) {
      int t = __shfl_up(tv, off, 64);
      if (lane >= off) tv += t;
    }
    if (lane < 16) wtot[lane] = tv;
  }
  __syncthreads();
  int out = (w ? wtot[w - 1] : 0) + incl;
  if (i < n) rowptr[i + 1] = out;
  if (tid == 1023) blksum[blockIdx.x] = out;
}

// pass 2 fused into pass 3: each block computes its own prefix of blksum (nblk <= 64)
__global__ __launch_bounds__(1024) void k_scan3(int* __restrict__ rowptr, const int* __restrict__ blksum, int n) {
  __shared__ int soff;
  if (threadIdx.x < 64) {
    int v = ((int)threadIdx.x < (int)blockIdx.x) ? blksum[threadIdx.x] : 0;
#pragma unroll
    for (int m = 1; m < 64; m <<= 1) v += __shfl_xor(v, m, 64);
    if (threadIdx.x == 0) soff = v;
  }
  __syncthreads();
  const int i = blockIdx.x * 1024 + threadIdx.x;
  if (i == 0) rowptr[0] = 0;
  if (i < n) rowptr[i + 1] += soff;
}

// cluster CSR: combine + full scan in ONE single-block kernel (NB multiple of 1024)
template <int NB>
__global__ __launch_bounds__(1024) void k_combscan(int* __restrict__ cnt, int* __restrict__ rowptr, int nslice) {
  __shared__ int sdeg[NB];
  __shared__ int wtot[16];
  const int tid = threadIdx.x, lane = tid & 63, w = tid >> 6;
  for (int d = tid; d < NB; d += 1024) {
    int acc = 0;
    for (int s = 0; s < nslice; s++) {
      int c = cnt[(size_t)s * NB + d];
      cnt[(size_t)s * NB + d] = acc;
      acc += c;
    }
    sdeg[d] = acc;
  }
  if (tid == 0) rowptr[0] = 0;
  __syncthreads();
  int carry = 0;
  for (int base = 0; base < NB; base += 1024) {
    int v = sdeg[base + tid];
    int incl = v;
#pragma unroll
    for (int off = 1; off < 64; off <<= 1) {
      int t = __shfl_up(incl, off, 64);
      if (lane >= off) incl += t;
    }
    if (lane == 63) wtot[w] = incl;
    __syncthreads();
    if (w == 0) {
      int tv = (lane < 16) ? wtot[lane] : 0;
#pragma unroll
      for (int off = 1; off < 16; off <<= 1) {
        int t = __shfl_up(tv, off, 64);
        if (lane >= off) tv += t;
      }
      if (lane < 16) wtot[lane] = tv;
    }
    __syncthreads();
    int out = carry + (w ? wtot[w - 1] : 0) + incl;
    rowptr[base + tid + 1] = out;
    carry += wtot[15];
    __syncthreads();
  }
}

// scatter pass: re-rank via fresh LDS histogram; one plain store per key.
template <int RSIZE, int NR, bool IDENT>
__global__ __launch_bounds__(256) void k_scat(const int* __restrict__ key, const int* __restrict__ val,
                                              const int* __restrict__ rowptr, const int* __restrict__ cnt,
                                              int* __restrict__ col, int n, int slen) {
  __shared__ int h[RSIZE];
  const int s = blockIdx.x / NR, r = blockIdx.x % NR;
  const int base = r * RSIZE;
  for (int i = threadIdx.x; i < RSIZE; i += 256) h[i] = 0;
  __syncthreads();
  const int NB = RSIZE * NR;
  const int i0 = s * slen, i1 = min(n, i0 + slen);
  for (int i = i0 + threadIdx.x * 4; i < i1; i += 1024) {
    int4 k4, v4;
    if (i + 3 < i1) {
      k4 = *reinterpret_cast<const int4*>(&key[i]);
      if (!IDENT) v4 = *reinterpret_cast<const int4*>(&val[i]);
    } else {
      k4.x = key[i];
      k4.y = (i + 1 < i1) ? key[i + 1] : -1;
      k4.z = (i + 2 < i1) ? key[i + 2] : -1;
      k4.w = (i + 3 < i1) ? key[i + 3] : -1;
      if (!IDENT) {
        v4.x = val[i];
        v4.y = (i + 1 < i1) ? val[i + 1] : 0;
        v4.z = (i + 2 < i1) ? val[i + 2] : 0;
        v4.w = (i + 3 < i1) ? val[i + 3] : 0;
      }
    }
    const int ks[4] = {k4.x, k4.y, k4.z, k4.w};
    const int vs[4] = {IDENT ? i : v4.x, IDENT ? i + 1 : v4.y, IDENT ? i + 2 : v4.z, IDENT ? i + 3 : v4.w};
#pragma unroll
    for (int u = 0; u < 4; u++) {
      int d = ks[u];
      int dr = d - base;
      if ((unsigned)dr < (unsigned)RSIZE) {
        int lr = atomicAdd(&h[dr], 1);
        int pos = rowptr[d] + cnt[(size_t)s * NB + d] + lr;
        col[pos] = vs[u];
      }
    }
  }
}

// ---------- weight prep: all 3 layers in one kernel ----------
struct PrepArgs {
  const float* w1[3];
  const float* w2[3];
  f16_t* o[3][4];  // w1t_hi, w1t_lo, w2t_hi, w2t_lo
};
__global__ void k_prep_all(PrepArgs a) {
  int i = blockIdx.x * 256 + threadIdx.x;
  int L, base;
  if (i < 8192) { L = 0; base = 0; }
  else if (i < 24576) { L = 1; base = 8192; }
  else if (i < 57344) { L = 2; base = 24576; }
  else return;
  const int cin = 64 << L;
  const int n1 = cin * 64;
  int j = i - base;
  if (j < n1) {
    int k = j >> 6, c = j & 63;
    float v = a.w1[L][j];
    f16_t hi = (f16_t)v;
    a.o[L][0][(size_t)c * cin + k] = hi;
    a.o[L][1][(size_t)c * cin + k] = (f16_t)(v - (float)hi);
  } else {
    int i2 = j - n1;
    int c = i2 / cin, jj = i2 & (cin - 1);
    float v = a.w2[L][i2];
    f16_t hi = (f16_t)v;
    a.o[L][2][(size_t)jj * 64 + c] = hi;
    a.o[L][3][(size_t)jj * 64 + c] = (f16_t)(v - (float)hi);
  }
}

// ---------- MFMA MLP v4: fused gather-max staging ----------
// Input row = [h (KCH*64 ch, materialized, stride SIN=KCH*64) | agg (gathered on the fly)].
// Gathered agg values are f16-exact (max of f16s) -> bit-identical to standalone agg.
template <int CIN, int KCH, int SOUT, typename TIN>
__global__ __launch_bounds__(256) void k_mlp(const TIN* __restrict__ xin,
                                             const int* __restrict__ rowptr, const int* __restrict__ col,
                                             const f16_t* __restrict__ w1t_hi, const f16_t* __restrict__ w1t_lo,
                                             const float* __restrict__ b1, const float* __restrict__ g,
                                             const float* __restrict__ be,
                                             const f16_t* __restrict__ w2t_hi, const f16_t* __restrict__ w2t_lo,
                                             const float* __restrict__ b2,
                                             ushort_t* __restrict__ xout, int N) {
  constexpr int KC = CIN / 64;
  constexpr int SIN = KCH * 64;
  __shared__ __align__(16) f16_t sB[2][4096];
  __shared__ __align__(16) f16_t sX[2][4096];
  __shared__ __align__(16) f16_t sH[2][4096];

  const int tid = threadIdx.x;
  const int wave = tid >> 6, lane = tid & 63;
  const int b = lane & 15, q = lane >> 4;
  const int nb = blockIdx.x * 64;
  const int nbW = nb + wave * 16;

  f32x4 acc1[4] = {};

  // ================= phase 1: H = X @ W1 =================
  for (int kc = 0; kc < KC; kc++) {
    __syncthreads();
#pragma unroll
    for (int half = 0; half < 2; half++) {
      int i = tid * 8 + half * 2048;
      int c = i >> 6, kk = i & 63;
      int t = c >> 4, bb = c & 15, kt = kk >> 5, qq = (kk >> 3) & 3;
      int dst = ((t * 2 + kt) * 64 + qq * 16 + bb) * 8;
      size_t src = (size_t)c * CIN + kc * 64 + kk;
      *reinterpret_cast<f16x8*>(&sB[0][dst]) = *reinterpret_cast<const f16x8*>(&w1t_hi[src]);
      *reinterpret_cast<f16x8*>(&sB[1][dst]) = *reinterpret_cast<const f16x8*>(&w1t_lo[src]);
    }
#pragma unroll
    for (int half = 0; half < 2; half++) {
      int i = tid * 8 + half * 2048;
      int n = i >> 6, kk = i & 63;
      int w = n >> 4, bb = n & 15, kt = kk >> 5, qq = (kk >> 3) & 3;
      int dst = ((w * 2 + kt) * 64 + qq * 16 + bb) * 8;
      int gn = nb + n;
      if (gn >= N) gn = N - 1;
      if constexpr (sizeof(TIN) == 4) {
        float f[8];
        *reinterpret_cast<float4*>(&f[0]) = *reinterpret_cast<const float4*>(&xin[(size_t)gn * SIN + kc * 64 + kk]);
        *reinterpret_cast<float4*>(&f[4]) = *reinterpret_cast<const float4*>(&xin[(size_t)gn * SIN + kc * 64 + kk + 4]);
        f16x8 vh, vl;
#pragma unroll
        for (int j = 0; j < 8; j++) {
          f16_t hi = (f16_t)f[j];
          vh[j] = hi;
          vl[j] = (f16_t)(f[j] - (float)hi);
        }
        *reinterpret_cast<f16x8*>(&sX[0][dst]) = vh;
        *reinterpret_cast<f16x8*>(&sX[1][dst]) = vl;
      } else {
        if (KCH == KC || kc < KCH) {
          *reinterpret_cast<f16x8*>(&sX[0][dst]) =
              *reinterpret_cast<const f16x8*>(&xin[(size_t)gn * SIN + kc * 64 + kk]);
        } else {
          // fused gather-max: agg channel range [c0, c0+8) of node gn
          const int c0 = (kc - KCH) * 64 + kk;
          const int beg = rowptr[gn], end = rowptr[gn + 1];
          float m[8];
#pragma unroll
          for (int p = 0; p < 8; p++) m[p] = -INFINITY;
          for (int e = beg; e < end; e += 4) {
            int idx[4];
#pragma unroll
            for (int u = 0; u < 4; u++) { int t2 = e + u; idx[u] = col[t2 < end ? t2 : e]; }
            uint4 rr[4];
#pragma unroll
            for (int u = 0; u < 4; u++)
              rr[u] = *reinterpret_cast<const uint4*>(&xin[(size_t)idx[u] * SIN + c0]);
#pragma unroll
            for (int u = 0; u < 4; u++) {
              float2 f0 = h2f2(rr[u].x), f1 = h2f2(rr[u].y), f2v = h2f2(rr[u].z), f3 = h2f2(rr[u].w);
              m[0] = fmaxf(m[0], f0.x); m[1] = fmaxf(m[1], f0.y);
              m[2] = fmaxf(m[2], f1.x); m[3] = fmaxf(m[3], f1.y);
              m[4] = fmaxf(m[4], f2v.x); m[5] = fmaxf(m[5], f2v.y);
              m[6] = fmaxf(m[6], f3.x); m[7] = fmaxf(m[7], f3.y);
            }
          }
          if (beg == end) {
#pragma unroll
            for (int p = 0; p < 8; p++) m[p] = 0.f;
          }
          uint4 pk = make_uint4(f2h2(m[0], m[1]), f2h2(m[2], m[3]), f2h2(m[4], m[5]), f2h2(m[6], m[7]));
          *reinterpret_cast<uint4*>(&sX[0][dst]) = pk;
        }
      }
    }
    __syncthreads();
#pragma unroll
    for (int kt = 0; kt < 2; kt++) {
      f16x8 a = *reinterpret_cast<const f16x8*>(&sX[0][((wave * 2 + kt) * 64 + lane) * 8]);
      f16x8 al;
      if constexpr (sizeof(TIN) == 4)
        al = *reinterpret_cast<const f16x8*>(&sX[1][((wave * 2 + kt) * 64 + lane) * 8]);
#pragma unroll
      for (int t = 0; t < 4; t++) {
        f16x8 bh = *reinterpret_cast<const f16x8*>(&sB[0][((t * 2 + kt) * 64 + lane) * 8]);
        f16x8 bl = *reinterpret_cast<const f16x8*>(&sB[1][((t * 2 + kt) * 64 + lane) * 8]);
        acc1[t] = __builtin_amdgcn_mfma_f32_16x16x32_f16(a, bh, acc1[t], 0, 0, 0);
        acc1[t] = __builtin_amdgcn_mfma_f32_16x16x32_f16(a, bl, acc1[t], 0, 0, 0);
        if constexpr (sizeof(TIN) == 4)
          acc1[t] = __builtin_amdgcn_mfma_f32_16x16x32_f16(al, bh, acc1[t], 0, 0, 0);
      }
    }
  }

  // ---- + b1, LayerNorm(64), *g + be, ReLU ----
  float b1v[4], gv[4], bev[4];
#pragma unroll
  for (int t = 0; t < 4; t++) {
    b1v[t] = b1[t * 16 + b];
    gv[t] = g[t * 16 + b];
    bev[t] = be[t * 16 + b];
  }
#pragma unroll
  for (int t = 0; t < 4; t++)
#pragma unroll
    for (int r = 0; r < 4; r++) acc1[t][r] += b1v[t];

  float mu[4], vv[4], rs[4];
#pragma unroll
  for (int r = 0; r < 4; r++) mu[r] = acc1[0][r] + acc1[1][r] + acc1[2][r] + acc1[3][r];
#pragma unroll
  for (int m = 1; m < 16; m <<= 1) {
#pragma unroll
    for (int r = 0; r < 4; r++) mu[r] += __shfl_xor(mu[r], m, 64);
  }
#pragma unroll
  for (int r = 0; r < 4; r++) mu[r] *= (1.f / 64.f);
#pragma unroll
  for (int r = 0; r < 4; r++) {
    float d0 = acc1[0][r] - mu[r], d1 = acc1[1][r] - mu[r];
    float d2 = acc1[2][r] - mu[r], d3 = acc1[3][r] - mu[r];
    vv[r] = d0 * d0 + d1 * d1 + d2 * d2 + d3 * d3;
  }
#pragma unroll
  for (int m = 1; m < 16; m <<= 1) {
#pragma unroll
    for (int r = 0; r < 4; r++) vv[r] += __shfl_xor(vv[r], m, 64);
  }
#pragma unroll
  for (int r = 0; r < 4; r++) rs[r] = rsqrtf(vv[r] * (1.f / 64.f) + 1e-5f);

  // ---- H -> per-wave LDS frags (hi/lo), A-layout; no barrier needed ----
#pragma unroll
  for (int t = 0; t < 4; t++) {
    const int kt = t >> 1;
    const int qq = (t & 1) * 2 + (b >> 3);
    const int jj = b & 7;
#pragma unroll
    for (int r = 0; r < 4; r++) {
      float h = (acc1[t][r] - mu[r]) * rs[r] * gv[t] + bev[t];
      h = fmaxf(h, 0.f);
      f16_t hh = (f16_t)h;
      int m = q * 4 + r;
      int dst = ((wave * 2 + kt) * 64 + qq * 16 + m) * 8 + jj;
      sH[0][dst] = hh;
      sH[1][dst] = (f16_t)(h - (float)hh);
    }
  }

  f16x8 ahi[2], alo[2];
#pragma unroll
  for (int kt = 0; kt < 2; kt++) {
    ahi[kt] = *reinterpret_cast<const f16x8*>(&sH[0][((wave * 2 + kt) * 64 + lane) * 8]);
    alo[kt] = *reinterpret_cast<const f16x8*>(&sH[1][((wave * 2 + kt) * 64 + lane) * 8]);
  }

  // ================= phase 2: OUT = H @ W2 + b2 =================
  for (int jc = 0; jc < KC; jc++) {
    __syncthreads();
#pragma unroll
    for (int half = 0; half < 2; half++) {
      int i = tid * 8 + half * 2048;
      int jjn = i >> 6, cc = i & 63;
      int t2 = jjn >> 4, bb = jjn & 15, kt = cc >> 5, qq = (cc >> 3) & 3;
      int dst = ((t2 * 2 + kt) * 64 + qq * 16 + bb) * 8;
      size_t src = (size_t)(jc * 64 + jjn) * 64 + cc;
      *reinterpret_cast<f16x8*>(&sB[0][dst]) = *reinterpret_cast<const f16x8*>(&w2t_hi[src]);
      *reinterpret_cast<f16x8*>(&sB[1][dst]) = *reinterpret_cast<const f16x8*>(&w2t_lo[src]);
    }
    __syncthreads();
#pragma unroll
    for (int t2 = 0; t2 < 4; t2++) {
      f32x4 acc = {};
#pragma unroll
      for (int kt = 0; kt < 2; kt++) {
        f16x8 bh = *reinterpret_cast<const f16x8*>(&sB[0][((t2 * 2 + kt) * 64 + lane) * 8]);
        f16x8 bl = *reinterpret_cast<const f16x8*>(&sB[1][((t2 * 2 + kt) * 64 + lane) * 8]);
        acc = __builtin_amdgcn_mfma_f32_16x16x32_f16(ahi[kt], bh, acc, 0, 0, 0);
        acc = __builtin_amdgcn_mfma_f32_16x16x32_f16(ahi[kt], bl, acc, 0, 0, 0);
        acc = __builtin_amdgcn_mfma_f32_16x16x32_f16(alo[kt], bh, acc, 0, 0, 0);
      }
      int col2 = jc * 64 + t2 * 16 + b;
      float b2v = b2[col2];
#pragma unroll
      for (int r = 0; r < 4; r++) {
        int node = nbW + q * 4 + r;
        if (node < N) {
          __half hv = __float2half_rn(acc[r] + b2v);
          xout[(size_t)node * SOUT + col2] = *reinterpret_cast<ushort_t*>(&hv);
        }
      }
    }
  }
}

// ---------- final scatter-max (layer 3 only): fills agg half of x3 ----------
template <int CIN, int UNR>
__global__ __launch_bounds__(256) void k_agg(ushort_t* __restrict__ xb, const int* __restrict__ rowptr,
                                             const int* __restrict__ col, int N) {
  constexpr int LPR = CIN / 8;
  constexpr int RPW = 64 / LPR;
  const int wid = (blockIdx.x * blockDim.x + threadIdx.x) >> 6;
  const int lane = threadIdx.x & 63;
  const int sub = lane / LPR;
  const int ll = lane % LPR;
  const int node = wid * RPW + sub;
  if (node >= N) return;
  const int beg = rowptr[node], end = rowptr[node + 1];
  float v[8];
#pragma unroll
  for (int p = 0; p < 8; p++) v[p] = -INFINITY;
  for (int e = beg; e < end; e += UNR) {
    int idx[UNR];
#pragma unroll
    for (int u = 0; u < UNR; u++) { int t = e + u; idx[u] = col[t < end ? t : e]; }
    uint4 r[UNR];
#pragma unroll
    for (int u = 0; u < UNR; u++)
      r[u] = *reinterpret_cast<const uint4*>(xb + (size_t)idx[u] * (2 * CIN) + ll * 8);
#pragma unroll
    for (int u = 0; u < UNR; u++) {
      float2 f0 = h2f2(r[u].x), f1 = h2f2(r[u].y), f2 = h2f2(r[u].z), f3 = h2f2(r[u].w);
      v[0] = fmaxf(v[0], f0.x); v[1] = fmaxf(v[1], f0.y);
      v[2] = fmaxf(v[2], f1.x); v[3] = fmaxf(v[3], f1.y);
      v[4] = fmaxf(v[4], f2.x); v[5] = fmaxf(v[5], f2.y);
      v[6] = fmaxf(v[6], f3.x); v[7] = fmaxf(v[7], f3.y);
    }
  }
  if (beg == end) {
#pragma unroll
    for (int p = 0; p < 8; p++) v[p] = 0.f;
  }
  *reinterpret_cast<uint4*>(xb + (size_t)node * (2 * CIN) + CIN + ll * 8) =
      make_uint4(f2h2(v[0], v[1]), f2h2(v[2], v[3]), f2h2(v[4], v[5]), f2h2(v[6], v[7]));
}

// ---------- cluster max-pool: wave per cluster, 512 f16 channels, x8 unroll ----------
__global__ __launch_bounds__(256) void k_pool(const ushort_t* __restrict__ x3, const int* __restrict__ rowptr,
                                              const int* __restrict__ col, float* __restrict__ pooled, int NC) {
  const int wid = (blockIdx.x * blockDim.x + threadIdx.x) >> 6;
  const int lane = threadIdx.x & 63;
  if (wid >= NC) return;
  const int beg = rowptr[wid], end = rowptr[wid + 1];
  float v[8];
#pragma unroll
  for (int p = 0; p < 8; p++) v[p] = -INFINITY;
  for (int e = beg; e < end; e += 8) {
    int idx[8];
#pragma unroll
    for (int u = 0; u < 8; u++) { int t = e + u; idx[u] = col[t < end ? t : e]; }
    uint4 r[8];
#pragma unroll
    for (int u = 0; u < 8; u++)
      r[u] = *reinterpret_cast<const uint4*>(x3 + (size_t)idx[u] * 512 + lane * 8);
#pragma unroll
    for (int u = 0; u < 8; u++) {
      float2 f0 = h2f2(r[u].x), f1 = h2f2(r[u].y), f2 = h2f2(r[u].z), f3 = h2f2(r[u].w);
      v[0] = fmaxf(v[0], f0.x); v[1] = fmaxf(v[1], f0.y);
      v[2] = fmaxf(v[2], f1.x); v[3] = fmaxf(v[3], f1.y);
      v[4] = fmaxf(v[4], f2.x); v[5] = fmaxf(v[5], f2.y);
      v[6] = fmaxf(v[6], f3.x); v[7] = fmaxf(v[7], f3.y);
    }
  }
  if (beg == end) {
#pragma unroll
    for (int p = 0; p < 8; p++) v[p] = 0.f;
  }
  float4* o = reinterpret_cast<float4*>(pooled + (size_t)wid * 512 + lane * 8);
  o[0] = make_float4(v[0], v[1], v[2], v[3]);
  o[1] = make_float4(v[4], v[5], v[6], v[7]);
}

// ---------- per-column sum of squares ----------
__global__ __launch_bounds__(256) void k_norm(const float* __restrict__ pooled, float* __restrict__ normsq, int NC) {
  const int c0 = threadIdx.x;
  const int c1 = threadIdx.x + 256;
  const int rows = (NC + gridDim.x - 1) / gridDim.x;
  float s0 = 0.f, s1 = 0.f;
  for (int rr = 0; rr < rows; rr++) {
    int r = blockIdx.x * rows + rr;
    if (r < NC) {
      float v0 = pooled[(size_t)r * 512 + c0];
      float v1 = pooled[(size_t)r * 512 + c1];
      s0 = fmaf(v0, v0, s0);
      s1 = fmaf(v1, v1, s1);
    }
  }
  atomicAdd(&normsq[c0], s0);
  atomicAdd(&normsq[c1], s1);
}

__global__ void k_final(const float* __restrict__ pooled, const float* __restrict__ normsq,
                        float* __restrict__ out, int n) {
  int i = blockIdx.x * blockDim.x + threadIdx.x;
  if (i >= n) return;
  int c = i & 511;
  out[i] = pooled[i] * rsqrtf(normsq[c]);
}

// ---------- launch ----------
extern "C" void kernel_launch(void* const* d_in, const int* in_sizes, int n_in,
                              void* d_out, int out_size, void* d_ws, size_t ws_size,
                              hipStream_t stream) {
  const int N = in_sizes[0] / 64;
  const int E = in_sizes[1] / 2;
  const int NC = out_size / 512;

  const float* x0 = (const float*)d_in[0];
  const int* ei = (const int*)d_in[1];
  const int* cluster = (const int*)d_in[2];

  const float* W[18];
  for (int k = 0; k < 18; k++) W[k] = (const float*)d_in[5 + k];

  // CSR counting-sort geometry
  constexpr int RSZ_E = 12544, NR_E = 4, NSL_E = 128;
  constexpr int RSZ_C = 5120, NR_C = 1, NSL_C = 32;
  const int NB_E = RSZ_E * NR_E;  // 50176
  const int NB_C = RSZ_C * NR_C;  // 5120 (multiple of 1024)
  const int slenE = (((E + NSL_E - 1) / NSL_E) + 3) & ~3;
  const int slenC = (((N + NSL_C - 1) / NSL_C) + 3) & ~3;

  char* p = (char*)d_ws;
  auto alloc = [&](size_t bytes) -> void* {
    void* r = (void*)p;
    p += (bytes + 255) & ~(size_t)255;
    return r;
  };
  ushort_t* x1h = (ushort_t*)alloc((size_t)N * 64 * 2);    // h only (stride 64)
  ushort_t* x2h = (ushort_t*)alloc((size_t)N * 128 * 2);   // h only (stride 128)
  ushort_t* x3h = (ushort_t*)alloc((size_t)N * 512 * 2);   // [h(256) | agg(256)]
  float* pooled = (float*)alloc((size_t)NC * 512 * 4);
  float* normsq = (float*)alloc((size_t)512 * 4);
  int* degE     = (int*)alloc((size_t)NB_E * 4);
  int* rowptrE  = (int*)alloc((size_t)(NB_E + 1) * 4);
  int* colE     = (int*)alloc((size_t)E * 4);
  int* cntE     = (int*)alloc((size_t)NSL_E * NB_E * 4);
  int* rowptrC  = (int*)alloc((size_t)(NB_C + 1) * 4);
  int* colC     = (int*)alloc((size_t)N * 4);
  int* cntC     = (int*)alloc((size_t)NSL_C * NB_C * 4);
  int* blkE     = (int*)alloc(64 * 4);
  // f16 hi/lo transposed weights per layer
  f16_t* wt[3][4];
  for (int L = 0; L < 3; L++) {
    int cin = 64 << L;
    for (int j = 0; j < 4; j++) wt[L][j] = (f16_t*)alloc((size_t)cin * 64 * 2);
  }

  hipMemsetAsync(normsq, 0, (size_t)512 * 4, stream);

  // weight prep (single kernel, all layers)
  PrepArgs pa;
  pa.w1[0] = W[0]; pa.w2[0] = W[4];
  pa.w1[1] = W[6]; pa.w2[1] = W[10];
  pa.w1[2] = W[12]; pa.w2[2] = W[16];
  for (int L = 0; L < 3; L++)
    for (int j = 0; j < 4; j++) pa.o[L][j] = wt[L][j];
  k_prep_all<<<(57344 + 255) / 256, 256, 0, stream>>>(pa);

  // ---- edge CSR (grouped by dst), atomic-free counting sort ----
  k_cnt<RSZ_E, NR_E><<<NSL_E * NR_E, 256, 0, stream>>>(ei + E, cntE, E, slenE);
  k_combine<<<(NB_E + 255) / 256, 256, 0, stream>>>(cntE, degE, NB_E, NSL_E);
  { int nbk = (NB_E + 1023) / 1024;
    k_scan1<<<nbk, 1024, 0, stream>>>(degE, rowptrE, blkE, NB_E);
    k_scan3<<<nbk, 1024, 0, stream>>>(rowptrE, blkE, NB_E); }
  k_scat<RSZ_E, NR_E, false><<<NSL_E * NR_E, 256, 0, stream>>>(ei + E, ei, rowptrE, cntE, colE, E, slenE);

  // ---- cluster CSR ----
  k_cnt<RSZ_C, NR_C><<<NSL_C * NR_C, 256, 0, stream>>>(cluster, cntC, N, slenC);
  k_combscan<NB_C><<<1, 1024, 0, stream>>>(cntC, rowptrC, NSL_C);
  k_scat<RSZ_C, NR_C, true><<<NSL_C * NR_C, 256, 0, stream>>>(cluster, nullptr, rowptrC, cntC, colC, N, slenC);

  const int nblk = (N + 63) / 64;
  // layer 0: cin=64, fp32 input, no gather; out -> x1h (stride 64)
  k_mlp<64, 1, 64, float><<<nblk, 256, 0, stream>>>(x0, nullptr, nullptr,
                                                    wt[0][0], wt[0][1], W[1], W[2], W[3],
                                                    wt[0][2], wt[0][3], W[5], x1h, N);
  // layer 1: cin=128 = [h1 | gather(h1)]; out -> x2h (stride 128)
  k_mlp<128, 1, 128, ushort_t><<<nblk, 256, 0, stream>>>(x1h, rowptrE, colE,
                                                         wt[1][0], wt[1][1], W[7], W[8], W[9],
                                                         wt[1][2], wt[1][3], W[11], x2h, N);
  // layer 2: cin=256 = [h2 | gather(h2)]; out -> x3h h-half (stride 512)
  k_mlp<256, 2, 512, ushort_t><<<nblk, 256, 0, stream>>>(x2h, rowptrE, colE,
                                                         wt[2][0], wt[2][1], W[13], W[14], W[15],
                                                         wt[2][2], wt[2][3], W[17], x3h, N);
  // final aggregation fills agg half of x3h
  { int waves = (N + 1) / 2; k_agg<256, 8><<<(waves * 64 + 255) / 256, 256, 0, stream>>>(x3h, rowptrE, colE, N); }

  // cluster max-pool + column L2 normalize
  k_pool<<<(NC * 64 + 255) / 256, 256, 0, stream>>>(x3h, rowptrC, colC, pooled, NC);
  k_norm<<<128, 256, 0, stream>>>(pooled, normsq, NC);
  k_final<<<(NC * 512 + 255) / 256, 256, 0, stream>>>(pooled, normsq, (float*)d_out, NC * 512);
}

// Round 12
// 359.783 us; speedup vs baseline: 1.2864x; 1.2864x over previous
//
#include <hip/hip_runtime.h>
#include <hip/hip_fp16.h>

typedef unsigned short ushort_t;
typedef unsigned int uint_t;
typedef _Float16 f16_t;
typedef __attribute__((ext_vector_type(8))) _Float16 f16x8;
typedef __attribute__((ext_vector_type(4))) float f32x4;

__device__ __forceinline__ float2 h2f2(uint_t u) {
  __half2 h = *reinterpret_cast<__half2*>(&u);
  return __half22float2(h);
}
__device__ __forceinline__ uint_t f2h2(float a, float b) {
  __half2 h = __floats2half2_rn(a, b);
  return *reinterpret_cast<uint_t*>(&h);
}

// ---------- CSR geometry ----------
// edge:   RSZ_E=12544, NR_E=4 -> NB_E=50176 bins; NSL_E=128 slices; 512 blocks
// cluster:RSZ_C=5120,  NR_C=1 -> NB_C=5120 bins;  NSL_C=32 slices;  32 blocks
#define RSZ_E 12544
#define NR_E 4
#define NSL_E 128
#define NB_E (RSZ_E * NR_E)
#define RSZ_C 5120
#define NSL_C 32
#define NB_C 5120

// ---------- merged count kernel: edge blocks [0,512), cluster blocks [512,544) ----------
__global__ __launch_bounds__(256) void k_cnt_all(const int* __restrict__ keyE, ushort_t* __restrict__ cntE,
                                                 int nE, int slenE,
                                                 const int* __restrict__ keyC, ushort_t* __restrict__ cntC,
                                                 int nC, int slenC) {
  __shared__ int h[RSZ_E];
  const bool edge = blockIdx.x < NSL_E * NR_E;
  const int RSIZE = edge ? RSZ_E : RSZ_C;
  const int NR = edge ? NR_E : 1;
  const int bid = edge ? blockIdx.x : blockIdx.x - NSL_E * NR_E;
  const int s = bid / NR, r = bid % NR;
  const int base = r * RSIZE;
  const int* key = edge ? keyE : keyC;
  ushort_t* cnt = edge ? cntE : cntC;
  const int n = edge ? nE : nC;
  const int slen = edge ? slenE : slenC;
  const int NB = edge ? NB_E : NB_C;

  for (int i = threadIdx.x; i < RSIZE; i += 256) h[i] = 0;
  __syncthreads();
  const int i0 = s * slen, i1 = min(n, i0 + slen);
  for (int i = i0 + threadIdx.x * 4; i < i1; i += 1024) {
    int4 k4;
    if (i + 3 < i1) {
      k4 = *reinterpret_cast<const int4*>(&key[i]);
    } else {
      k4.x = key[i];
      k4.y = (i + 1 < i1) ? key[i + 1] : -1;
      k4.z = (i + 2 < i1) ? key[i + 2] : -1;
      k4.w = (i + 3 < i1) ? key[i + 3] : -1;
    }
    int d;
    d = k4.x - base; if ((unsigned)d < (unsigned)RSIZE) atomicAdd(&h[d], 1);
    d = k4.y - base; if ((unsigned)d < (unsigned)RSIZE) atomicAdd(&h[d], 1);
    d = k4.z - base; if ((unsigned)d < (unsigned)RSIZE) atomicAdd(&h[d], 1);
    d = k4.w - base; if ((unsigned)d < (unsigned)RSIZE) atomicAdd(&h[d], 1);
  }
  __syncthreads();
  for (int i = threadIdx.x; i < RSIZE; i += 256) cnt[(size_t)s * NB + base + i] = (ushort_t)h[i];
}

// ---------- merged combine: blocks [0,49) edge per-bin slice-scan; block 49 cluster combine+scan ----------
__global__ __launch_bounds__(1024) void k_combine_all(ushort_t* __restrict__ cntE, int* __restrict__ degE,
                                                      ushort_t* __restrict__ cntC, int* __restrict__ rowptrC) {
  __shared__ int sdeg[NB_C];
  __shared__ int wtot[16];
  if (blockIdx.x < 49) {
    const int d = blockIdx.x * 1024 + threadIdx.x;  // 49*1024 == NB_E
    int acc = 0;
    for (int s = 0; s < NSL_E; s++) {
      int c = cntE[(size_t)s * NB_E + d];
      cntE[(size_t)s * NB_E + d] = (ushort_t)acc;
      acc += c;
    }
    degE[d] = acc;
    return;
  }
  // cluster: combine over 32 slices then full scan of 5120 bins in one block
  const int tid = threadIdx.x, lane = tid & 63, w = tid >> 6;
  for (int d = tid; d < NB_C; d += 1024) {
    int acc = 0;
    for (int s = 0; s < NSL_C; s++) {
      int c = cntC[(size_t)s * NB_C + d];
      cntC[(size_t)s * NB_C + d] = (ushort_t)acc;
      acc += c;
    }
    sdeg[d] = acc;
  }
  if (tid == 0) rowptrC[0] = 0;
  __syncthreads();
  int carry = 0;
  for (int base = 0; base < NB_C; base += 1024) {
    int v = sdeg[base + tid];
    int incl = v;
#pragma unroll
    for (int off = 1; off < 64; off <<= 1) {
      int t = __shfl_up(incl, off, 64);
      if (lane >= off) incl += t;
    }
    if (lane == 63) wtot[w] = incl;
    __syncthreads();
    if (w == 0) {
      int tv = (lane < 16) ? wtot[lane] : 0;
#pragma unroll
      for (int off = 1; off < 16; off <<= 1) {
        int t = __shfl_up(tv, off, 64);
        if (lane >= off) tv += t;
      }
      if (lane < 16) wtot[lane] = tv;
    }
    __syncthreads();
    int out = carry + (w ? wtot[w - 1] : 0) + incl;
    rowptrC[base + tid + 1] = out;
    carry += wtot[15];
    __syncthreads();
  }
}

// ---------- edge hierarchical scan ----------
__global__ __launch_bounds__(1024) void k_scan1(const int* __restrict__ deg, int* __restrict__ rowptr,
                                                int* __restrict__ blksum, int n) {
  __shared__ int wtot[16];
  const int tid = threadIdx.x, lane = tid & 63, w = tid >> 6;
  const int i = blockIdx.x * 1024 + tid;
  int v = (i < n) ? deg[i] : 0;
  int incl = v;
#pragma unroll
  for (int off = 1; off < 64; off <<= 1) {
    int t = __shfl_up(incl, off, 64);
    if (lane >= off) incl += t;
  }
  if (lane == 63) wtot[w] = incl;
  __syncthreads();
  if (w == 0) {
    int tv = (lane < 16) ? wtot[lane] : 0;
#pragma unroll
    for (int off = 1; off < 16; off <<= 1) {
      int t = __shfl_up(tv, off, 64);
      if (lane >= off) tv += t;
    }
    if (lane < 16) wtot[lane] = tv;
  }
  __syncthreads();
  int out = (w ? wtot[w - 1] : 0) + incl;
  if (i < n) rowptr[i + 1] = out;
  if (tid == 1023) blksum[blockIdx.x] = out;
}

__global__ __launch_bounds__(1024) void k_scan3(int* __restrict__ rowptr, const int* __restrict__ blksum, int n) {
  __shared__ int soff;
  if (threadIdx.x < 64) {
    int v = ((int)threadIdx.x < (int)blockIdx.x) ? blksum[threadIdx.x] : 0;
#pragma unroll
    for (int m = 1; m < 64; m <<= 1) v += __shfl_xor(v, m, 64);
    if (threadIdx.x == 0) soff = v;
  }
  __syncthreads();
  const int i = blockIdx.x * 1024 + threadIdx.x;
  if (i == 0) rowptr[0] = 0;
  if (i < n) rowptr[i + 1] += soff;
}

// ---------- merged scatter: edge blocks [0,512), cluster blocks [512,544) ----------
__global__ __launch_bounds__(256) void k_scat_all(const int* __restrict__ keyE, const int* __restrict__ valE,
                                                  const int* __restrict__ rowptrE, const ushort_t* __restrict__ cntE,
                                                  int* __restrict__ colE, int nE, int slenE,
                                                  const int* __restrict__ keyC, const int* __restrict__ rowptrC,
                                                  const ushort_t* __restrict__ cntC, int* __restrict__ colC,
                                                  int nC, int slenC) {
  __shared__ int h[RSZ_E];
  const bool edge = blockIdx.x < NSL_E * NR_E;
  const int RSIZE = edge ? RSZ_E : RSZ_C;
  const int NR = edge ? NR_E : 1;
  const int bid = edge ? blockIdx.x : blockIdx.x - NSL_E * NR_E;
  const int s = bid / NR, r = bid % NR;
  const int base = r * RSIZE;
  const int* key = edge ? keyE : keyC;
  const int* rowptr = edge ? rowptrE : rowptrC;
  const ushort_t* cnt = edge ? cntE : cntC;
  int* col = edge ? colE : colC;
  const int n = edge ? nE : nC;
  const int slen = edge ? slenE : slenC;
  const int NB = edge ? NB_E : NB_C;

  for (int i = threadIdx.x; i < RSIZE; i += 256) h[i] = 0;
  __syncthreads();
  const int i0 = s * slen, i1 = min(n, i0 + slen);
  for (int i = i0 + threadIdx.x * 4; i < i1; i += 1024) {
    int4 k4, v4;
    if (i + 3 < i1) {
      k4 = *reinterpret_cast<const int4*>(&key[i]);
      if (edge) v4 = *reinterpret_cast<const int4*>(&valE[i]);
    } else {
      k4.x = key[i];
      k4.y = (i + 1 < i1) ? key[i + 1] : -1;
      k4.z = (i + 2 < i1) ? key[i + 2] : -1;
      k4.w = (i + 3 < i1) ? key[i + 3] : -1;
      if (edge) {
        v4.x = valE[i];
        v4.y = (i + 1 < i1) ? valE[i + 1] : 0;
        v4.z = (i + 2 < i1) ? valE[i + 2] : 0;
        v4.w = (i + 3 < i1) ? valE[i + 3] : 0;
      }
    }
    const int ks[4] = {k4.x, k4.y, k4.z, k4.w};
    const int vs[4] = {edge ? v4.x : i, edge ? v4.y : i + 1, edge ? v4.z : i + 2, edge ? v4.w : i + 3};
#pragma unroll
    for (int u = 0; u < 4; u++) {
      int d = ks[u];
      int dr = d - base;
      if ((unsigned)dr < (unsigned)RSIZE) {
        int lr = atomicAdd(&h[dr], 1);
        int pos = rowptr[d] + cnt[(size_t)s * NB + d] + lr;
        col[pos] = vs[u];
      }
    }
  }
}

// ---------- weight prep: all 3 layers in one kernel (+ normsq zeroing) ----------
struct PrepArgs {
  const float* w1[3];
  const float* w2[3];
  f16_t* o[3][4];  // w1t_hi, w1t_lo, w2t_hi, w2t_lo
  float* normsq;
};
__global__ void k_prep_all(PrepArgs a) {
  int i = blockIdx.x * 256 + threadIdx.x;
  if (i < 512) a.normsq[i] = 0.f;
  int L, base;
  if (i < 8192) { L = 0; base = 0; }
  else if (i < 24576) { L = 1; base = 8192; }
  else if (i < 57344) { L = 2; base = 24576; }
  else return;
  const int cin = 64 << L;
  const int n1 = cin * 64;
  int j = i - base;
  if (j < n1) {
    int k = j >> 6, c = j & 63;
    float v = a.w1[L][j];
    f16_t hi = (f16_t)v;
    a.o[L][0][(size_t)c * cin + k] = hi;
    a.o[L][1][(size_t)c * cin + k] = (f16_t)(v - (float)hi);
  } else {
    int i2 = j - n1;
    int c = i2 / cin, jj = i2 & (cin - 1);
    float v = a.w2[L][i2];
    f16_t hi = (f16_t)v;
    a.o[L][2][(size_t)jj * 64 + c] = hi;
    a.o[L][3][(size_t)jj * 64 + c] = (f16_t)(v - (float)hi);
  }
}

// ---------- MFMA MLP v3 (round-10 form): LDS-staged fragments ----------
// input stride CIN ([h|agg] of previous layer); output h-half of stride-2*CIN buffer.
template <int CIN, typename TIN>
__global__ __launch_bounds__(256) void k_mlp(const TIN* __restrict__ xin,
                                             const f16_t* __restrict__ w1t_hi, const f16_t* __restrict__ w1t_lo,
                                             const float* __restrict__ b1, const float* __restrict__ g,
                                             const float* __restrict__ be,
                                             const f16_t* __restrict__ w2t_hi, const f16_t* __restrict__ w2t_lo,
                                             const float* __restrict__ b2,
                                             ushort_t* __restrict__ xout, int N) {
  constexpr int KC = CIN / 64;
  __shared__ __align__(16) f16_t sB[2][4096];
  __shared__ __align__(16) f16_t sX[2][4096];
  __shared__ __align__(16) f16_t sH[2][4096];

  const int tid = threadIdx.x;
  const int wave = tid >> 6, lane = tid & 63;
  const int b = lane & 15, q = lane >> 4;
  const int nb = blockIdx.x * 64;
  const int nbW = nb + wave * 16;

  f32x4 acc1[4] = {};

  // ================= phase 1: H = X @ W1 =================
  for (int kc = 0; kc < KC; kc++) {
    __syncthreads();
#pragma unroll
    for (int half = 0; half < 2; half++) {
      int i = tid * 8 + half * 2048;
      int c = i >> 6, kk = i & 63;
      int t = c >> 4, bb = c & 15, kt = kk >> 5, qq = (kk >> 3) & 3;
      int dst = ((t * 2 + kt) * 64 + qq * 16 + bb) * 8;
      size_t src = (size_t)c * CIN + kc * 64 + kk;
      *reinterpret_cast<f16x8*>(&sB[0][dst]) = *reinterpret_cast<const f16x8*>(&w1t_hi[src]);
      *reinterpret_cast<f16x8*>(&sB[1][dst]) = *reinterpret_cast<const f16x8*>(&w1t_lo[src]);
    }
#pragma unroll
    for (int half = 0; half < 2; half++) {
      int i = tid * 8 + half * 2048;
      int n = i >> 6, kk = i & 63;
      int w = n >> 4, bb = n & 15, kt = kk >> 5, qq = (kk >> 3) & 3;
      int dst = ((w * 2 + kt) * 64 + qq * 16 + bb) * 8;
      int gn = nb + n;
      if (gn >= N) gn = N - 1;
      if constexpr (sizeof(TIN) == 4) {
        float f[8];
        *reinterpret_cast<float4*>(&f[0]) = *reinterpret_cast<const float4*>(&xin[(size_t)gn * CIN + kc * 64 + kk]);
        *reinterpret_cast<float4*>(&f[4]) = *reinterpret_cast<const float4*>(&xin[(size_t)gn * CIN + kc * 64 + kk + 4]);
        f16x8 vh, vl;
#pragma unroll
        for (int j = 0; j < 8; j++) {
          f16_t hi = (f16_t)f[j];
          vh[j] = hi;
          vl[j] = (f16_t)(f[j] - (float)hi);
        }
        *reinterpret_cast<f16x8*>(&sX[0][dst]) = vh;
        *reinterpret_cast<f16x8*>(&sX[1][dst]) = vl;
      } else {
        *reinterpret_cast<f16x8*>(&sX[0][dst]) =
            *reinterpret_cast<const f16x8*>(&xin[(size_t)gn * CIN + kc * 64 + kk]);
      }
    }
    __syncthreads();
#pragma unroll
    for (int kt = 0; kt < 2; kt++) {
      f16x8 a = *reinterpret_cast<const f16x8*>(&sX[0][((wave * 2 + kt) * 64 + lane) * 8]);
      f16x8 al;
      if constexpr (sizeof(TIN) == 4)
        al = *reinterpret_cast<const f16x8*>(&sX[1][((wave * 2 + kt) * 64 + lane) * 8]);
#pragma unroll
      for (int t = 0; t < 4; t++) {
        f16x8 bh = *reinterpret_cast<const f16x8*>(&sB[0][((t * 2 + kt) * 64 + lane) * 8]);
        f16x8 bl = *reinterpret_cast<const f16x8*>(&sB[1][((t * 2 + kt) * 64 + lane) * 8]);
        acc1[t] = __builtin_amdgcn_mfma_f32_16x16x32_f16(a, bh, acc1[t], 0, 0, 0);
        acc1[t] = __builtin_amdgcn_mfma_f32_16x16x32_f16(a, bl, acc1[t], 0, 0, 0);
        if constexpr (sizeof(TIN) == 4)
          acc1[t] = __builtin_amdgcn_mfma_f32_16x16x32_f16(al, bh, acc1[t], 0, 0, 0);
      }
    }
  }

  // ---- + b1, LayerNorm(64), *g + be, ReLU ----
  float b1v[4], gv[4], bev[4];
#pragma unroll
  for (int t = 0; t < 4; t++) {
    b1v[t] = b1[t * 16 + b];
    gv[t] = g[t * 16 + b];
    bev[t] = be[t * 16 + b];
  }
#pragma unroll
  for (int t = 0; t < 4; t++)
#pragma unroll
    for (int r = 0; r < 4; r++) acc1[t][r] += b1v[t];

  float mu[4], vv[4], rs[4];
#pragma unroll
  for (int r = 0; r < 4; r++) mu[r] = acc1[0][r] + acc1[1][r] + acc1[2][r] + acc1[3][r];
#pragma unroll
  for (int m = 1; m < 16; m <<= 1) {
#pragma unroll
    for (int r = 0; r < 4; r++) mu[r] += __shfl_xor(mu[r], m, 64);
  }
#pragma unroll
  for (int r = 0; r < 4; r++) mu[r] *= (1.f / 64.f);
#pragma unroll
  for (int r = 0; r < 4; r++) {
    float d0 = acc1[0][r] - mu[r], d1 = acc1[1][r] - mu[r];
    float d2 = acc1[2][r] - mu[r], d3 = acc1[3][r] - mu[r];
    vv[r] = d0 * d0 + d1 * d1 + d2 * d2 + d3 * d3;
  }
#pragma unroll
  for (int m = 1; m < 16; m <<= 1) {
#pragma unroll
    for (int r = 0; r < 4; r++) vv[r] += __shfl_xor(vv[r], m, 64);
  }
#pragma unroll
  for (int r = 0; r < 4; r++) rs[r] = rsqrtf(vv[r] * (1.f / 64.f) + 1e-5f);

  // ---- H -> per-wave LDS frags (hi/lo), A-layout; no barrier needed ----
#pragma unroll
  for (int t = 0; t < 4; t++) {
    const int kt = t >> 1;
    const int qq = (t & 1) * 2 + (b >> 3);
    const int jj = b & 7;
#pragma unroll
    for (int r = 0; r < 4; r++) {
      float h = (acc1[t][r] - mu[r]) * rs[r] * gv[t] + bev[t];
      h = fmaxf(h, 0.f);
      f16_t hh = (f16_t)h;
      int m = q * 4 + r;
      int dst = ((wave * 2 + kt) * 64 + qq * 16 + m) * 8 + jj;
      sH[0][dst] = hh;
      sH[1][dst] = (f16_t)(h - (float)hh);
    }
  }

  f16x8 ahi[2], alo[2];
#pragma unroll
  for (int kt = 0; kt < 2; kt++) {
    ahi[kt] = *reinterpret_cast<const f16x8*>(&sH[0][((wave * 2 + kt) * 64 + lane) * 8]);
    alo[kt] = *reinterpret_cast<const f16x8*>(&sH[1][((wave * 2 + kt) * 64 + lane) * 8]);
  }

  // ================= phase 2: OUT = H @ W2 + b2 =================
  for (int jc = 0; jc < KC; jc++) {
    __syncthreads();
#pragma unroll
    for (int half = 0; half < 2; half++) {
      int i = tid * 8 + half * 2048;
      int jjn = i >> 6, cc = i & 63;
      int t2 = jjn >> 4, bb = jjn & 15, kt = cc >> 5, qq = (cc >> 3) & 3;
      int dst = ((t2 * 2 + kt) * 64 + qq * 16 + bb) * 8;
      size_t src = (size_t)(jc * 64 + jjn) * 64 + cc;
      *reinterpret_cast<f16x8*>(&sB[0][dst]) = *reinterpret_cast<const f16x8*>(&w2t_hi[src]);
      *reinterpret_cast<f16x8*>(&sB[1][dst]) = *reinterpret_cast<const f16x8*>(&w2t_lo[src]);
    }
    __syncthreads();
#pragma unroll
    for (int t2 = 0; t2 < 4; t2++) {
      f32x4 acc = {};
#pragma unroll
      for (int kt = 0; kt < 2; kt++) {
        f16x8 bh = *reinterpret_cast<const f16x8*>(&sB[0][((t2 * 2 + kt) * 64 + lane) * 8]);
        f16x8 bl = *reinterpret_cast<const f16x8*>(&sB[1][((t2 * 2 + kt) * 64 + lane) * 8]);
        acc = __builtin_amdgcn_mfma_f32_16x16x32_f16(ahi[kt], bh, acc, 0, 0, 0);
        acc = __builtin_amdgcn_mfma_f32_16x16x32_f16(ahi[kt], bl, acc, 0, 0, 0);
        acc = __builtin_amdgcn_mfma_f32_16x16x32_f16(alo[kt], bh, acc, 0, 0, 0);
      }
      int col2 = jc * 64 + t2 * 16 + b;
      float b2v = b2[col2];
#pragma unroll
      for (int r = 0; r < 4; r++) {
        int node = nbW + q * 4 + r;
        if (node < N) {
          __half hv = __float2half_rn(acc[r] + b2v);
          xout[(size_t)node * (2 * CIN) + col2] = *reinterpret_cast<ushort_t*>(&hv);
        }
      }
    }
  }
}

// ---------- scatter-max as CSR gather-max (16 B/lane, UNR loads in flight/thread) ----------
template <int CIN, int UNR>
__global__ __launch_bounds__(256) void k_agg(ushort_t* __restrict__ xb, const int* __restrict__ rowptr,
                                             const int* __restrict__ col, int N) {
  constexpr int LPR = CIN / 8;
  constexpr int RPW = 64 / LPR;
  const int wid = (blockIdx.x * blockDim.x + threadIdx.x) >> 6;
  const int lane = threadIdx.x & 63;
  const int sub = lane / LPR;
  const int ll = lane % LPR;
  const int node = wid * RPW + sub;
  if (node >= N) return;
  const int beg = rowptr[node], end = rowptr[node + 1];
  float v[8];
#pragma unroll
  for (int p = 0; p < 8; p++) v[p] = -INFINITY;
  for (int e = beg; e < end; e += UNR) {
    int idx[UNR];
#pragma unroll
    for (int u = 0; u < UNR; u++) { int t = e + u; idx[u] = col[t < end ? t : e]; }
    uint4 r[UNR];
#pragma unroll
    for (int u = 0; u < UNR; u++)
      r[u] = *reinterpret_cast<const uint4*>(xb + (size_t)idx[u] * (2 * CIN) + ll * 8);
#pragma unroll
    for (int u = 0; u < UNR; u++) {
      float2 f0 = h2f2(r[u].x), f1 = h2f2(r[u].y), f2 = h2f2(r[u].z), f3 = h2f2(r[u].w);
      v[0] = fmaxf(v[0], f0.x); v[1] = fmaxf(v[1], f0.y);
      v[2] = fmaxf(v[2], f1.x); v[3] = fmaxf(v[3], f1.y);
      v[4] = fmaxf(v[4], f2.x); v[5] = fmaxf(v[5], f2.y);
      v[6] = fmaxf(v[6], f3.x); v[7] = fmaxf(v[7], f3.y);
    }
  }
  if (beg == end) {
#pragma unroll
    for (int p = 0; p < 8; p++) v[p] = 0.f;
  }
  *reinterpret_cast<uint4*>(xb + (size_t)node * (2 * CIN) + CIN + ll * 8) =
      make_uint4(f2h2(v[0], v[1]), f2h2(v[2], v[3]), f2h2(v[4], v[5]), f2h2(v[6], v[7]));
}

// ---------- cluster max-pool: wave per cluster, 512 f16 channels, x8 unroll ----------
__global__ __launch_bounds__(256) void k_pool(const ushort_t* __restrict__ x3, const int* __restrict__ rowptr,
                                              const int* __restrict__ col, float* __restrict__ pooled, int NC) {
  const int wid = (blockIdx.x * blockDim.x + threadIdx.x) >> 6;
  const int lane = threadIdx.x & 63;
  if (wid >= NC) return;
  const int beg = rowptr[wid], end = rowptr[wid + 1];
  float v[8];
#pragma unroll
  for (int p = 0; p < 8; p++) v[p] = -INFINITY;
  for (int e = beg; e < end; e += 8) {
    int idx[8];
#pragma unroll
    for (int u = 0; u < 8; u++) { int t = e + u; idx[u] = col[t < end ? t : e]; }
    uint4 r[8];
#pragma unroll
    for (int u = 0; u < 8; u++)
      r[u] = *reinterpret_cast<const uint4*>(x3 + (size_t)idx[u] * 512 + lane * 8);
#pragma unroll
    for (int u = 0; u < 8; u++) {
      float2 f0 = h2f2(r[u].x), f1 = h2f2(r[u].y), f2 = h2f2(r[u].z), f3 = h2f2(r[u].w);
      v[0] = fmaxf(v[0], f0.x); v[1] = fmaxf(v[1], f0.y);
      v[2] = fmaxf(v[2], f1.x); v[3] = fmaxf(v[3], f1.y);
      v[4] = fmaxf(v[4], f2.x); v[5] = fmaxf(v[5], f2.y);
      v[6] = fmaxf(v[6], f3.x); v[7] = fmaxf(v[7], f3.y);
    }
  }
  if (beg == end) {
#pragma unroll
    for (int p = 0; p < 8; p++) v[p] = 0.f;
  }
  float4* o = reinterpret_cast<float4*>(pooled + (size_t)wid * 512 + lane * 8);
  o[0] = make_float4(v[0], v[1], v[2], v[3]);
  o[1] = make_float4(v[4], v[5], v[6], v[7]);
}

// ---------- per-column sum of squares ----------
__global__ __launch_bounds__(256) void k_norm(const float* __restrict__ pooled, float* __restrict__ normsq, int NC) {
  const int c0 = threadIdx.x;
  const int c1 = threadIdx.x + 256;
  const int rows = (NC + gridDim.x - 1) / gridDim.x;
  float s0 = 0.f, s1 = 0.f;
  for (int rr = 0; rr < rows; rr++) {
    int r = blockIdx.x * rows + rr;
    if (r < NC) {
      float v0 = pooled[(size_t)r * 512 + c0];
      float v1 = pooled[(size_t)r * 512 + c1];
      s0 = fmaf(v0, v0, s0);
      s1 = fmaf(v1, v1, s1);
    }
  }
  atomicAdd(&normsq[c0], s0);
  atomicAdd(&normsq[c1], s1);
}

__global__ void k_final(const float* __restrict__ pooled, const float* __restrict__ normsq,
                        float* __restrict__ out, int n) {
  int i = blockIdx.x * blockDim.x + threadIdx.x;
  if (i >= n) return;
  int c = i & 511;
  out[i] = pooled[i] * rsqrtf(normsq[c]);
}

// ---------- launch ----------
extern "C" void kernel_launch(void* const* d_in, const int* in_sizes, int n_in,
                              void* d_out, int out_size, void* d_ws, size_t ws_size,
                              hipStream_t stream) {
  const int N = in_sizes[0] / 64;
  const int E = in_sizes[1] / 2;
  const int NC = out_size / 512;

  const float* x0 = (const float*)d_in[0];
  const int* ei = (const int*)d_in[1];
  const int* cluster = (const int*)d_in[2];

  const float* W[18];
  for (int k = 0; k < 18; k++) W[k] = (const float*)d_in[5 + k];

  const int slenE = (((E + NSL_E - 1) / NSL_E) + 3) & ~3;
  const int slenC = (((N + NSL_C - 1) / NSL_C) + 3) & ~3;

  char* p = (char*)d_ws;
  auto alloc = [&](size_t bytes) -> void* {
    void* r = (void*)p;
    p += (bytes + 255) & ~(size_t)255;
    return r;
  };
  ushort_t* x1h = (ushort_t*)alloc((size_t)N * 128 * 2);   // [h64|agg64]
  ushort_t* x2h = (ushort_t*)alloc((size_t)N * 256 * 2);   // [h128|agg128]
  ushort_t* x3h = (ushort_t*)alloc((size_t)N * 512 * 2);   // [h256|agg256]
  float* pooled = (float*)alloc((size_t)NC * 512 * 4);
  float* normsq = (float*)alloc((size_t)512 * 4);
  int* degE     = (int*)alloc((size_t)NB_E * 4);
  int* rowptrE  = (int*)alloc((size_t)(NB_E + 1) * 4);
  int* colE     = (int*)alloc((size_t)E * 4);
  ushort_t* cntE = (ushort_t*)alloc((size_t)NSL_E * NB_E * 2);
  int* rowptrC  = (int*)alloc((size_t)(NB_C + 1) * 4);
  int* colC     = (int*)alloc((size_t)N * 4);
  ushort_t* cntC = (ushort_t*)alloc((size_t)NSL_C * NB_C * 2);
  int* blkE     = (int*)alloc(64 * 4);
  f16_t* wt[3][4];
  for (int L = 0; L < 3; L++) {
    int cin = 64 << L;
    for (int j = 0; j < 4; j++) wt[L][j] = (f16_t*)alloc((size_t)cin * 64 * 2);
  }

  // 1) weight prep + normsq zero
  PrepArgs pa;
  pa.w1[0] = W[0]; pa.w2[0] = W[4];
  pa.w1[1] = W[6]; pa.w2[1] = W[10];
  pa.w1[2] = W[12]; pa.w2[2] = W[16];
  for (int L = 0; L < 3; L++)
    for (int j = 0; j < 4; j++) pa.o[L][j] = wt[L][j];
  pa.normsq = normsq;
  k_prep_all<<<(57344 + 255) / 256, 256, 0, stream>>>(pa);

  // 2-6) CSR build (edge + cluster merged)
  k_cnt_all<<<NSL_E * NR_E + NSL_C, 256, 0, stream>>>(ei + E, cntE, E, slenE, cluster, cntC, N, slenC);
  k_combine_all<<<50, 1024, 0, stream>>>(cntE, degE, cntC, rowptrC);
  k_scan1<<<49, 1024, 0, stream>>>(degE, rowptrE, blkE, NB_E);
  k_scan3<<<49, 1024, 0, stream>>>(rowptrE, blkE, NB_E);
  k_scat_all<<<NSL_E * NR_E + NSL_C, 256, 0, stream>>>(ei + E, ei, rowptrE, cntE, colE, E, slenE,
                                                       cluster, rowptrC, cntC, colC, N, slenC);

  const int nblk = (N + 63) / 64;
  // 7-12) layers
  k_mlp<64, float><<<nblk, 256, 0, stream>>>(x0, wt[0][0], wt[0][1], W[1], W[2], W[3],
                                             wt[0][2], wt[0][3], W[5], x1h, N);
  { int waves = (N + 7) / 8; k_agg<64, 4><<<(waves * 64 + 255) / 256, 256, 0, stream>>>(x1h, rowptrE, colE, N); }
  k_mlp<128, ushort_t><<<nblk, 256, 0, stream>>>(x1h, wt[1][0], wt[1][1], W[7], W[8], W[9],
                                                 wt[1][2], wt[1][3], W[11], x2h, N);
  { int waves = (N + 3) / 4; k_agg<128, 8><<<(waves * 64 + 255) / 256, 256, 0, stream>>>(x2h, rowptrE, colE, N); }
  k_mlp<256, ushort_t><<<nblk, 256, 0, stream>>>(x2h, wt[2][0], wt[2][1], W[13], W[14], W[15],
                                                 wt[2][2], wt[2][3], W[17], x3h, N);
  { int waves = (N + 1) / 2; k_agg<256, 8><<<(waves * 64 + 255) / 256, 256, 0, stream>>>(x3h, rowptrE, colE, N); }

  // 13-15) pool + normalize
  k_pool<<<(NC * 64 + 255) / 256, 256, 0, stream>>>(x3h, rowptrC, colC, pooled, NC);
  k_norm<<<128, 256, 0, stream>>>(pooled, normsq, NC);
  k_final<<<(NC * 512 + 255) / 256, 256, 0, stream>>>(pooled, normsq, (float*)d_out, NC * 512);
}